// Round 19
// baseline (144.333 us; speedup 1.0000x reference)
//
#include <hip/hip_runtime.h>

typedef __attribute__((ext_vector_type(8))) short short8;
typedef __attribute__((ext_vector_type(4))) float f32x4;

#define MFMA16(a,b,c) __builtin_amdgcn_mfma_f32_16x16x32_bf16(a,b,c,0,0,0)

__device__ __forceinline__ unsigned short f2bf(float f){
  unsigned int u = __float_as_uint(f);
  u += 0x7FFF + ((u>>16)&1);
  return (unsigned short)(u>>16);
}

__device__ __forceinline__ float fexp2(float x){
#if __has_builtin(__builtin_amdgcn_exp2f)
  return __builtin_amdgcn_exp2f(x);
#else
  return exp2f(x);
#endif
}

__device__ __forceinline__ void gl_lds16(const void* g, void* l){
  __builtin_amdgcn_global_load_lds((const __attribute__((address_space(1))) void*)g,
                                   (__attribute__((address_space(3))) void*)l, 16, 0, 0);
}

// Fused prep: converts x, Wq, Wk, Wv, Wo to bf16 and writes the 2 lambda outs.
// grid 8192x256; regions are block-aligned (1024 f32 per block).
__global__ void prep_k(const float* __restrict__ x,
                       const float* __restrict__ Wq, const float* __restrict__ Wk,
                       const float* __restrict__ Wv, const float* __restrict__ Wo,
                       const float* __restrict__ u,
                       unsigned short* __restrict__ xb,
                       unsigned short* __restrict__ Wqkvb,
                       unsigned short* __restrict__ Wob,
                       float* __restrict__ out){
  const int bid = blockIdx.x;
  const float* src;
  unsigned short* dst;
  int lb;                       // local block index within region
  if (bid < 4096)      { src = x;  dst = xb;              lb = bid; }
  else if (bid < 5120) { src = Wq; dst = Wqkvb;           lb = bid - 4096; }
  else if (bid < 6144) { src = Wk; dst = Wqkvb + 1048576; lb = bid - 5120; }
  else if (bid < 7168) { src = Wv; dst = Wqkvb + 2097152; lb = bid - 6144; }
  else                 { src = Wo; dst = Wob;             lb = bid - 7168; }
  const int i = (lb*256 + threadIdx.x)*4;
  float4 v = *(const float4*)(src + i);
  ushort4 o;
  o.x = f2bf(v.x); o.y = f2bf(v.y); o.z = f2bf(v.z); o.w = f2bf(v.w);
  *(ushort4*)(dst + i) = o;
  if (bid == 0 && threadIdx.x < 2)
    out[4194304 + threadIdx.x] = 10.f*__expf(-5.f*u[threadIdx.x]);
}

// C[m,n] = sum_k A[m,k]*Bw[n,k]  (Bw row-major [N,K] = W, i.e. y = x W^T)
// R19: XCD-chunked block swizzle (grid linear count divisible by 8).
template<int MODE>
__global__ __launch_bounds__(256) void gemm_bt(
  const unsigned short* __restrict__ A,
  const unsigned short* __restrict__ Bw,
  const float* __restrict__ bias0, const float* __restrict__ bias1, const float* __restrict__ bias2,
  unsigned short* __restrict__ Qo, unsigned short* __restrict__ Ko, unsigned short* __restrict__ VTo,
  float* __restrict__ Co,
  int M, int N, int K)
{
  __shared__ unsigned short As[2][128*32];
  __shared__ unsigned short Bs[2][128*32];
  const int tid = threadIdx.x;
  const int nbx = gridDim.x;
  const int lin = blockIdx.x + blockIdx.y*nbx;
  const int cpx = (nbx*gridDim.y) >> 3;
  const int fsw = (lin & 7)*cpx + (lin >> 3);
  const int m0 = (fsw/nbx)*128, n0 = (fsw%nbx)*128;
  const int w = tid>>6, lane = tid&63, lr = lane&15, lg = lane>>4;
  const int wm = w>>1, wn = w&1;
  const int nk = K/32;

  auto stage = [&](int buf, int kt){
    const unsigned short* Ag = A + (size_t)m0*K + kt*32;
    const unsigned short* Bg = Bw + (size_t)n0*K + kt*32;
    #pragma unroll
    for (int it=0; it<2; ++it){
      int slot = it*256 + tid;
      gl_lds16(Ag + (size_t)(slot>>2)*K + (slot&3)*8, &As[buf][slot*8]);
    }
    #pragma unroll
    for (int it=0; it<2; ++it){
      int slot = it*256 + tid;
      gl_lds16(Bg + (size_t)(slot>>2)*K + (slot&3)*8, &Bs[buf][slot*8]);
    }
  };

  f32x4 acc[4][4] = {};
  stage(0,0);
  for (int kt=0; kt<nk; ++kt){
    int cur = kt&1;
    __syncthreads();
    if (kt+1 < nk) stage(cur^1, kt+1);
    short8 af[4], bfr[4];
    #pragma unroll
    for (int i=0;i<4;++i) af[i]  = *(const short8*)&As[cur][(wm*64 + i*16 + lr)*32 + lg*8];
    #pragma unroll
    for (int j=0;j<4;++j) bfr[j] = *(const short8*)&Bs[cur][(wn*64 + j*16 + lr)*32 + lg*8];
    #pragma unroll
    for (int i=0;i<4;++i)
      #pragma unroll
      for (int j=0;j<4;++j)
        acc[i][j] = MFMA16(af[i], bfr[j], acc[i][j]);
  }

  #pragma unroll
  for (int i=0;i<4;++i){
    #pragma unroll
    for (int j=0;j<4;++j){
      const int n  = n0 + wn*64 + j*16 + lr;
      const int mb = m0 + wm*64 + i*16 + lg*4;
      if (MODE==0){
        const int which = n>>10, nn = n&1023;
        const float bv = (which==0) ? bias0[nn] : (which==1) ? bias1[nn] : bias2[nn];
        const int h = nn>>6, hd = nn&63;
        #pragma unroll
        for (int r=0;r<4;++r){
          const int m = mb + r;
          const int b = m>>11, s = m&2047;
          const unsigned short u = f2bf(acc[i][j][r] + bv);
          const size_t bh = (size_t)(b*16 + h);
          if (which==0)      Qo[(bh*2048 + s)*64 + hd] = u;
          else if (which==1) Ko[(bh*2048 + s)*64 + hd] = u;
          else               VTo[(bh*64 + hd)*2048 + s] = u;
        }
      } else {
        const float bv = bias0[n];
        #pragma unroll
        for (int r=0;r<4;++r){
          const int m = mb + r;
          Co[(size_t)m*N + n] = acc[i][j][r] + bv;
        }
      }
    }
  }
}

// Attention — R18-verified core (KVBLK=32, 4 waves, seg-major staging,
// static-max exp2 softmax, trunc P pack, triple-buffer K/V + counted-vmcnt
// barrier, XCD-chunked swizzle).
// R19: P-roundtrip pipelined — P(KT) is written in BODY(KT-1) and read at
// BODY(KT) start; p_lds is TRIPLE-buffered so every rotating resource has
// period 3 (matching the 3-body unroll). Scores live within one body only.
// BODY(KT): pa(KT)+vf(KT) reads -> BAR -> STAGE(KT+3) -> QK(KT+1) -> PV(KT)
//           -> SOFT(KT+1) writes p_lds[(KT+1)%3].
// grid(32, 32), 256 thr. Lane (lr,lg): s{0,1}[r] = S[q0+lg*4+r][k0+t*16+lr].
__global__ __launch_bounds__(256, 4) void attn_k(
  const unsigned short* __restrict__ Qb,
  const unsigned short* __restrict__ Kb,
  const unsigned short* __restrict__ VT,
  const float* __restrict__ u_prev,
  unsigned short* __restrict__ Out)  // [B,S,H*HD] bf16
{
  // XCD-chunked swizzle (bijective, 1024 = 8*128)
  const int lin = blockIdx.x + (blockIdx.y << 5);
  const int f   = ((lin & 7) << 7) + (lin >> 3);
  const int qt  = f & 31, bh = f >> 5;
  const int b = bh>>4, h = bh&15;
  const float lam = 10.f * __expf(-5.f * u_prev[b]);
  const float nlamb = -lam * 1.4426950408889634f;   // -lam * log2(e)
  const int tid = threadIdx.x;
  const int w = tid>>6, lane = tid&63, lr = lane&15, lg = lane>>4;
  const int q0 = qt*64 + w*16;

  const unsigned short* Qp = Qb + (size_t)bh*2048*64;
  const unsigned short* Kp = Kb + (size_t)bh*2048*64;
  const unsigned short* Vp = VT + (size_t)bh*64*2048;

  // Seg-major LDS layouts (16B chunk index c):
  //  K (32 k-rows x 64 d-cols):  c = seg*32 + row, seg in [0,8)
  //  V (64 hd-rows x 32 k-cols): c = seg*64 + row, seg in [0,4)
  __shared__ unsigned short Ks[3][2048];
  __shared__ unsigned short Vs[3][2048];
  __shared__ unsigned short p_lds[4][3][16][40];   // [wave][pbuf][q][k], 80B rows

  // hoisted stage addresses
  const unsigned short* ksrc = Kp + (tid&31)*64 + (tid>>5)*8;            // + kt*2048
  const unsigned short* vsrc = Vp + (size_t)(tid&63)*2048 + (tid>>6)*8;  // + kt*32
  unsigned short* kd0 = &Ks[0][tid*8];
  unsigned short* kd1 = &Ks[1][tid*8];
  unsigned short* kd2 = &Ks[2][tid*8];
  unsigned short* vd0 = &Vs[0][tid*8];
  unsigned short* vd1 = &Vs[1][tid*8];
  unsigned short* vd2 = &Vs[2][tid*8];

  // hoisted fragment addresses (imm-offset reads from these)
  const unsigned short* kf0p = &Ks[0][(lg*32+lr)*8];   // +0,+1024,+128,+1152
  const unsigned short* kf1p = &Ks[1][(lg*32+lr)*8];
  const unsigned short* kf2p = &Ks[2][(lg*32+lr)*8];
  const unsigned short* vf0p = &Vs[0][(lg*64+lr)*8];   // +0,+128,+256,+384
  const unsigned short* vf1p = &Vs[1][(lg*64+lr)*8];
  const unsigned short* vf2p = &Vs[2][(lg*64+lr)*8];
  const unsigned short* pap  = &p_lds[w][0][lr][lg*8]; // + pbuf*640
  unsigned short* pwp = &p_lds[w][0][lg*4][lr];        // + pbuf*640 + r*40 (+16)

  // Q as A-fragment: lane holds Q[q0+lr, lg*8+j (+32)]
  short8 qf0 = *(const short8*)&Qp[(size_t)(q0+lr)*64 +      lg*8];
  short8 qf1 = *(const short8*)&Qp[(size_t)(q0+lr)*64 + 32 + lg*8];

  const float c1 = 0.18033688011112042f;   // log2(e)/8
  float l_run[4] = {0.f, 0.f, 0.f, 0.f};
  f32x4 o0 = {}, o1 = {}, o2 = {}, o3 = {};
  const f32x4 zf = {};
  f32x4 s0, s1;   // scores live within one body only

#define STAGE_(KD, VD, KT) do{ const int kw_ = (KT)&63; \
    gl_lds16(ksrc + ((size_t)kw_<<11), (KD)); \
    gl_lds16(vsrc + (kw_<<5), (VD)); }while(0)

  // counted-vmcnt barrier: age-2 stage complete, newest stage stays in flight
#define BAR_ do{ \
    asm volatile("s_waitcnt vmcnt(2) lgkmcnt(0)\n\ts_barrier" ::: "memory"); \
    __builtin_amdgcn_sched_barrier(0); }while(0)

#define QKM_(KP) do{ \
    short8 ka_ = *(const short8*)(KP); \
    short8 kb_ = *(const short8*)((KP)+1024); \
    short8 kc_ = *(const short8*)((KP)+128); \
    short8 kd_ = *(const short8*)((KP)+1152); \
    s0 = MFMA16(qf0, ka_, zf); s0 = MFMA16(qf1, kb_, s0); \
    s1 = MFMA16(qf0, kc_, zf); s1 = MFMA16(qf1, kd_, s1); }while(0)

  // SOFT_(KT, PWOFF): softmax on s0/s1 for tile KT -> P into p buffer PWOFF
#define SOFT_(KT, PWOFF) do{ \
    const int k0_ = (KT)*32; \
    const int cls_ = (k0_ > q0 + 117 || k0_ < q0 - 133) ? 2 \
                   : (k0_ >= q0 - 87 && k0_ <= q0 + 71) ? 0 : 1; \
    _Pragma("unroll") \
    for (int r=0;r<4;++r){ \
      const int qi_ = q0 + lg*4 + r; \
      float b0 = 0.f, b1 = 0.f; \
      if (cls_ == 2){ b0 = nlamb; b1 = nlamb; } \
      else if (cls_ == 1){ \
        int d0 = qi_ - (k0_ + lr);      if (d0<0) d0 = -d0; \
        int d1 = qi_ - (k0_ + 16 + lr); if (d1<0) d1 = -d1; \
        if (d0 > 102) b0 = nlamb; \
        if (d1 > 102) b1 = nlamb; \
      } \
      const float p0 = fexp2(fmaf(s0[r], c1, b0)); \
      const float p1 = fexp2(fmaf(s1[r], c1, b1)); \
      l_run[r] += p0 + p1; \
      pwp[(PWOFF) + r*40]      = (unsigned short)(__float_as_uint(p0)>>16); \
      pwp[(PWOFF) + r*40 + 16] = (unsigned short)(__float_as_uint(p1)>>16); \
    } }while(0)

  // BODY(KT): read pa(KT) [p buf PROFF] + vf(KT) [buf KT%3]; BAR; stage KT+3
  // into buf KT%3; QK(KT+1) from buf (KT+1)%3; PV(KT); SOFT(KT+1) -> PWOFF.
#define BODY_(KT, VFPC, KDC, VDC, KFPN, PROFF, PWOFF) do{ \
    short8 pa_  = *(const short8*)(pap + (PROFF)); \
    short8 vfa_ = *(const short8*)(VFPC); \
    short8 vfb_ = *(const short8*)((VFPC)+128); \
    short8 vfc_ = *(const short8*)((VFPC)+256); \
    short8 vfd_ = *(const short8*)((VFPC)+384); \
    BAR_; \
    STAGE_((KDC), (VDC), (KT)+3); \
    QKM_((KFPN)); \
    o0 = MFMA16(pa_, vfa_, o0); \
    o1 = MFMA16(pa_, vfb_, o1); \
    o2 = MFMA16(pa_, vfc_, o2); \
    o3 = MFMA16(pa_, vfd_, o3); \
    SOFT_((KT)+1, PWOFF); }while(0)

  // prologue: stage tiles 0,1,2; BAR (vmcnt(2) completes stages 0,1);
  // scores(0); P(0) -> p buf 0
  STAGE_(kd0, vd0, 0);
  STAGE_(kd1, vd1, 1);
  STAGE_(kd2, vd2, 2);
  BAR_;
  QKM_(kf0p);
  SOFT_(0, 0);

  for (int it=0; it<21; ++it){
    const int kt = it*3;
    BODY_(kt,   vf0p, kd0, vd0, kf1p, 0,    640);
    BODY_(kt+1, vf1p, kd1, vd1, kf2p, 640,  1280);
    BODY_(kt+2, vf2p, kd2, vd2, kf0p, 1280, 0);
  }
  // tail: tile 63 (V buf 0, P buf 0; P(63) written by BODY(62), V(63) staged
  // by BODY(60) and completed at BODY(62)'s barrier)
  {
    short8 pa_  = *(const short8*)(pap);
    short8 vfa_ = *(const short8*)(vf0p);
    short8 vfb_ = *(const short8*)(vf0p+128);
    short8 vfc_ = *(const short8*)(vf0p+256);
    short8 vfd_ = *(const short8*)(vf0p+384);
    o0 = MFMA16(pa_, vfa_, o0);
    o1 = MFMA16(pa_, vfb_, o1);
    o2 = MFMA16(pa_, vfc_, o2);
    o3 = MFMA16(pa_, vfd_, o3);
  }
#undef BODY_
#undef SOFT_
#undef QKM_
#undef BAR_
#undef STAGE_

  #pragma unroll
  for (int off=1; off<16; off<<=1)
    #pragma unroll
    for (int r=0;r<4;++r)
      l_run[r] += __shfl_xor(l_run[r], off, 64);

  #pragma unroll
  for (int r=0;r<4;++r){
    const int qi = q0 + lg*4 + r;
    const float linv = 1.0f / l_run[r];
    unsigned short* op = &Out[((size_t)b*2048 + qi)*1024 + h*64 + lr];
    op[0]  = f2bf(o0[r] * linv);
    op[16] = f2bf(o1[r] * linv);
    op[32] = f2bf(o2[r] * linv);
    op[48] = f2bf(o3[r] * linv);
  }
}

extern "C" void kernel_launch(void* const* d_in, const int* in_sizes, int n_in,
                              void* d_out, int out_size, void* d_ws, size_t ws_size,
                              hipStream_t stream){
  const float* x  = (const float*)d_in[0];
  const float* u  = (const float*)d_in[1];
  const float* Wq = (const float*)d_in[2];
  const float* bq = (const float*)d_in[3];
  const float* Wk = (const float*)d_in[4];
  const float* bk = (const float*)d_in[5];
  const float* Wv = (const float*)d_in[6];
  const float* bv = (const float*)d_in[7];
  const float* Wo = (const float*)d_in[8];
  const float* bo = (const float*)d_in[9];
  float* out = (float*)d_out;

  unsigned char* ws = (unsigned char*)d_ws;
  unsigned short* xb    = (unsigned short*)(ws);              // 4096x1024 bf16 (8MB)
  unsigned short* attnb = xb;                                 // reused after GEMM1
  unsigned short* Wqkvb = (unsigned short*)(ws + 8388608);    // 3072x1024 (6MB)
  unsigned short* Wob   = (unsigned short*)(ws + 14680064);   // 1024x1024 (2MB)
  unsigned short* Qb2   = (unsigned short*)(ws + 16777216);   // [B,H,S,HD] (8MB)
  unsigned short* Kb2   = (unsigned short*)(ws + 25165824);   // [B,H,S,HD] (8MB)
  unsigned short* VTb   = (unsigned short*)(ws + 33554432);   // [B,H,HD,S] (8MB)

  prep_k<<<8192, 256, 0, stream>>>(x, Wq, Wk, Wv, Wo, u, xb, Wqkvb, Wob, out);

  gemm_bt<0><<<dim3(24,32), 256, 0, stream>>>(xb, Wqkvb, bq, bk, bv,
                                              Qb2, Kb2, VTb, nullptr, 4096, 3072, 1024);
  attn_k<<<dim3(32,32), 256, 0, stream>>>(Qb2, Kb2, VTb, u, attnb);
  gemm_bt<1><<<dim3(8,32), 256, 0, stream>>>(attnb, Wob, bo, nullptr, nullptr,
                                             nullptr, nullptr, nullptr, out, 4096, 1024, 1024);
}

// Round 20
// 139.484 us; speedup vs baseline: 1.0348x; 1.0348x over previous
//
#include <hip/hip_runtime.h>

typedef __attribute__((ext_vector_type(8))) short short8;
typedef __attribute__((ext_vector_type(4))) float f32x4;

#define MFMA16(a,b,c) __builtin_amdgcn_mfma_f32_16x16x32_bf16(a,b,c,0,0,0)

__device__ __forceinline__ unsigned short f2bf(float f){
  unsigned int u = __float_as_uint(f);
  u += 0x7FFF + ((u>>16)&1);
  return (unsigned short)(u>>16);
}

__device__ __forceinline__ float fexp2(float x){
#if __has_builtin(__builtin_amdgcn_exp2f)
  return __builtin_amdgcn_exp2f(x);
#else
  return exp2f(x);
#endif
}

__device__ __forceinline__ void gl_lds16(const void* g, void* l){
  __builtin_amdgcn_global_load_lds((const __attribute__((address_space(1))) void*)g,
                                   (__attribute__((address_space(3))) void*)l, 16, 0, 0);
}

// Fused prep: converts x, Wq, Wk, Wv, Wo to bf16 and writes the 2 lambda outs.
__global__ void prep_k(const float* __restrict__ x,
                       const float* __restrict__ Wq, const float* __restrict__ Wk,
                       const float* __restrict__ Wv, const float* __restrict__ Wo,
                       const float* __restrict__ u,
                       unsigned short* __restrict__ xb,
                       unsigned short* __restrict__ Wqkvb,
                       unsigned short* __restrict__ Wob,
                       float* __restrict__ out){
  const int bid = blockIdx.x;
  const float* src;
  unsigned short* dst;
  int lb;
  if (bid < 4096)      { src = x;  dst = xb;              lb = bid; }
  else if (bid < 5120) { src = Wq; dst = Wqkvb;           lb = bid - 4096; }
  else if (bid < 6144) { src = Wk; dst = Wqkvb + 1048576; lb = bid - 5120; }
  else if (bid < 7168) { src = Wv; dst = Wqkvb + 2097152; lb = bid - 6144; }
  else                 { src = Wo; dst = Wob;             lb = bid - 7168; }
  const int i = (lb*256 + threadIdx.x)*4;
  float4 v = *(const float4*)(src + i);
  ushort4 o;
  o.x = f2bf(v.x); o.y = f2bf(v.y); o.z = f2bf(v.z); o.w = f2bf(v.w);
  *(ushort4*)(dst + i) = o;
  if (bid == 0 && threadIdx.x < 2)
    out[4194304 + threadIdx.x] = 10.f*__expf(-5.f*u[threadIdx.x]);
}

// C[m,n] = sum_k A[m,k]*Bw[n,k]  (Bw row-major [N,K] = W, i.e. y = x W^T)
// XCD-chunked block swizzle. MODE 0: V-blocks (which==2) use LDS-transposed
// epilogue for coalesced 16B writes along s (was 8B-per-4KB-stride scatter).
template<int MODE>
__global__ __launch_bounds__(256) void gemm_bt(
  const unsigned short* __restrict__ A,
  const unsigned short* __restrict__ Bw,
  const float* __restrict__ bias0, const float* __restrict__ bias1, const float* __restrict__ bias2,
  unsigned short* __restrict__ Qo, unsigned short* __restrict__ Ko, unsigned short* __restrict__ VTo,
  float* __restrict__ Co,
  int M, int N, int K)
{
  __shared__ unsigned short SM[2][2][128*32];   // As = SM[0], Bs = SM[1]
  unsigned short (*As)[128*32] = SM[0];
  unsigned short (*Bs)[128*32] = SM[1];
  const int tid = threadIdx.x;
  const int nbx = gridDim.x;
  const int lin = blockIdx.x + blockIdx.y*nbx;
  const int cpx = (nbx*gridDim.y) >> 3;
  const int fsw = (lin & 7)*cpx + (lin >> 3);
  const int m0 = (fsw/nbx)*128, n0 = (fsw%nbx)*128;
  const int w = tid>>6, lane = tid&63, lr = lane&15, lg = lane>>4;
  const int wm = w>>1, wn = w&1;
  const int nk = K/32;

  auto stage = [&](int buf, int kt){
    const unsigned short* Ag = A + (size_t)m0*K + kt*32;
    const unsigned short* Bg = Bw + (size_t)n0*K + kt*32;
    #pragma unroll
    for (int it=0; it<2; ++it){
      int slot = it*256 + tid;
      gl_lds16(Ag + (size_t)(slot>>2)*K + (slot&3)*8, &As[buf][slot*8]);
    }
    #pragma unroll
    for (int it=0; it<2; ++it){
      int slot = it*256 + tid;
      gl_lds16(Bg + (size_t)(slot>>2)*K + (slot&3)*8, &Bs[buf][slot*8]);
    }
  };

  f32x4 acc[4][4] = {};
  stage(0,0);
  for (int kt=0; kt<nk; ++kt){
    int cur = kt&1;
    __syncthreads();
    if (kt+1 < nk) stage(cur^1, kt+1);
    short8 af[4], bfr[4];
    #pragma unroll
    for (int i=0;i<4;++i) af[i]  = *(const short8*)&As[cur][(wm*64 + i*16 + lr)*32 + lg*8];
    #pragma unroll
    for (int j=0;j<4;++j) bfr[j] = *(const short8*)&Bs[cur][(wn*64 + j*16 + lr)*32 + lg*8];
    #pragma unroll
    for (int i=0;i<4;++i)
      #pragma unroll
      for (int j=0;j<4;++j)
        acc[i][j] = MFMA16(af[i], bfr[j], acc[i][j]);
  }

  if (MODE==0 && (n0>>10)==2){
    // ---- V epilogue: stage C^T in halves, write coalesced along s ----
    unsigned short (*Ct)[136] = (unsigned short(*)[136])&SM[0][0][0];  // [64][136]
    const int nb = n0 - 2048;   // nn_w base
    #pragma unroll
    for (int hh=0; hh<2; ++hh){
      __syncthreads();          // prior LDS reads (or prior half writes) drained
      if (wn == hh){
        #pragma unroll
        for (int i=0;i<4;++i)
          #pragma unroll
          for (int j=0;j<4;++j){
            const int nl = j*16 + lr;                       // 0..63
            const float bv = bias2[nb + hh*64 + nl];
            ushort4 pk;
            pk.x = f2bf(acc[i][j][0] + bv);
            pk.y = f2bf(acc[i][j][1] + bv);
            pk.z = f2bf(acc[i][j][2] + bv);
            pk.w = f2bf(acc[i][j][3] + bv);
            *(ushort4*)&Ct[nl][wm*64 + i*16 + lg*4] = pk;
          }
      }
      __syncthreads();
      #pragma unroll
      for (int it=0; it<4; ++it){
        const int idx = it*256 + tid;        // 0..1023
        const int nl = idx >> 4, mc = idx & 15;
        short8 vv = *(const short8*)&Ct[nl][mc*8];
        const int nn = nb + hh*64 + nl;
        const int h = nn>>6, hd = nn&63;
        const int mg = m0 + mc*8;
        const int b = mg>>11, s = mg&2047;
        *(short8*)&VTo[((size_t)(b*16 + h)*64 + hd)*2048 + s] = vv;
      }
    }
    return;
  }

  #pragma unroll
  for (int i=0;i<4;++i){
    #pragma unroll
    for (int j=0;j<4;++j){
      const int n  = n0 + wn*64 + j*16 + lr;
      const int mb = m0 + wm*64 + i*16 + lg*4;
      if (MODE==0){
        const int which = n>>10, nn = n&1023;
        const float bv = (which==0) ? bias0[nn] : bias1[nn];
        const int h = nn>>6, hd = nn&63;
        #pragma unroll
        for (int r=0;r<4;++r){
          const int m = mb + r;
          const int b = m>>11, s = m&2047;
          const unsigned short u = f2bf(acc[i][j][r] + bv);
          const size_t bh = (size_t)(b*16 + h);
          if (which==0) Qo[(bh*2048 + s)*64 + hd] = u;
          else          Ko[(bh*2048 + s)*64 + hd] = u;
        }
      } else {
        const float bv = bias0[n];
        #pragma unroll
        for (int r=0;r<4;++r){
          const int m = mb + r;
          Co[(size_t)m*N + n] = acc[i][j][r] + bv;
        }
      }
    }
  }
}

// Attention — R18-verified (76.7µs): KVBLK=32, 4 waves, seg-major staging,
// static-max exp2 softmax, trunc P pack, triple-buffer K/V + counted-vmcnt
// barrier, one-tile QK lookahead, XCD-chunked swizzle, period-3 scores.
__global__ __launch_bounds__(256, 4) void attn_k(
  const unsigned short* __restrict__ Qb,
  const unsigned short* __restrict__ Kb,
  const unsigned short* __restrict__ VT,
  const float* __restrict__ u_prev,
  unsigned short* __restrict__ Out)  // [B,S,H*HD] bf16
{
  const int lin = blockIdx.x + (blockIdx.y << 5);
  const int f   = ((lin & 7) << 7) + (lin >> 3);
  const int qt  = f & 31, bh = f >> 5;
  const int b = bh>>4, h = bh&15;
  const float lam = 10.f * __expf(-5.f * u_prev[b]);
  const float nlamb = -lam * 1.4426950408889634f;   // -lam * log2(e)
  const int tid = threadIdx.x;
  const int w = tid>>6, lane = tid&63, lr = lane&15, lg = lane>>4;
  const int q0 = qt*64 + w*16;

  const unsigned short* Qp = Qb + (size_t)bh*2048*64;
  const unsigned short* Kp = Kb + (size_t)bh*2048*64;
  const unsigned short* Vp = VT + (size_t)bh*64*2048;

  __shared__ unsigned short Ks[3][2048];
  __shared__ unsigned short Vs[3][2048];
  __shared__ unsigned short p_lds[4][16][40];   // 80B row stride

  const unsigned short* ksrc = Kp + (tid&31)*64 + (tid>>5)*8;            // + kt*2048
  const unsigned short* vsrc = Vp + (size_t)(tid&63)*2048 + (tid>>6)*8;  // + kt*32
  unsigned short* kd0 = &Ks[0][tid*8];
  unsigned short* kd1 = &Ks[1][tid*8];
  unsigned short* kd2 = &Ks[2][tid*8];
  unsigned short* vd0 = &Vs[0][tid*8];
  unsigned short* vd1 = &Vs[1][tid*8];
  unsigned short* vd2 = &Vs[2][tid*8];

  const unsigned short* kf0p = &Ks[0][(lg*32+lr)*8];
  const unsigned short* kf1p = &Ks[1][(lg*32+lr)*8];
  const unsigned short* kf2p = &Ks[2][(lg*32+lr)*8];
  const unsigned short* vf0p = &Vs[0][(lg*64+lr)*8];
  const unsigned short* vf1p = &Vs[1][(lg*64+lr)*8];
  const unsigned short* vf2p = &Vs[2][(lg*64+lr)*8];
  const unsigned short* pap  = &p_lds[w][lr][lg*8];
  unsigned short* pwp = &p_lds[w][lg*4][lr];

  short8 qf0 = *(const short8*)&Qp[(size_t)(q0+lr)*64 +      lg*8];
  short8 qf1 = *(const short8*)&Qp[(size_t)(q0+lr)*64 + 32 + lg*8];

  const float c1 = 0.18033688011112042f;   // log2(e)/8
  float l_run[4] = {0.f, 0.f, 0.f, 0.f};
  f32x4 o0 = {}, o1 = {}, o2 = {}, o3 = {};
  const f32x4 zf = {};
  f32x4 sA0, sA1, sB0, sB1, sC0, sC1;

#define STAGE_(KD, VD, KT) do{ const int kw_ = (KT)&63; \
    gl_lds16(ksrc + ((size_t)kw_<<11), (KD)); \
    gl_lds16(vsrc + (kw_<<5), (VD)); }while(0)

#define BAR_ do{ \
    asm volatile("s_waitcnt vmcnt(2) lgkmcnt(0)\n\ts_barrier" ::: "memory"); \
    __builtin_amdgcn_sched_barrier(0); }while(0)

#define QKM_(KP, S0, S1) do{ \
    short8 ka_ = *(const short8*)(KP); \
    short8 kb_ = *(const short8*)((KP)+1024); \
    short8 kc_ = *(const short8*)((KP)+128); \
    short8 kd_ = *(const short8*)((KP)+1152); \
    S0 = MFMA16(qf0, ka_, zf); S0 = MFMA16(qf1, kb_, S0); \
    S1 = MFMA16(qf0, kc_, zf); S1 = MFMA16(qf1, kd_, S1); }while(0)

#define SOFT_(KT, SIN0, SIN1) do{ \
    const int k0_ = (KT)*32; \
    const int cls_ = (k0_ > q0 + 117 || k0_ < q0 - 133) ? 2 \
                   : (k0_ >= q0 - 87 && k0_ <= q0 + 71) ? 0 : 1; \
    _Pragma("unroll") \
    for (int r=0;r<4;++r){ \
      const int qi_ = q0 + lg*4 + r; \
      float b0 = 0.f, b1 = 0.f; \
      if (cls_ == 2){ b0 = nlamb; b1 = nlamb; } \
      else if (cls_ == 1){ \
        int d0 = qi_ - (k0_ + lr);      if (d0<0) d0 = -d0; \
        int d1 = qi_ - (k0_ + 16 + lr); if (d1<0) d1 = -d1; \
        if (d0 > 102) b0 = nlamb; \
        if (d1 > 102) b1 = nlamb; \
      } \
      const float p0 = fexp2(fmaf((SIN0)[r], c1, b0)); \
      const float p1 = fexp2(fmaf((SIN1)[r], c1, b1)); \
      l_run[r] += p0 + p1; \
      pwp[r*40]      = (unsigned short)(__float_as_uint(p0)>>16); \
      pwp[r*40 + 16] = (unsigned short)(__float_as_uint(p1)>>16); \
    } }while(0)

#define BODY_(KT, VFPC, KDC, VDC, KFPN, SIN0, SIN1, SOUT0, SOUT1) do{ \
    SOFT_((KT), SIN0, SIN1); \
    short8 vfa_ = *(const short8*)(VFPC); \
    short8 vfb_ = *(const short8*)((VFPC)+128); \
    short8 vfc_ = *(const short8*)((VFPC)+256); \
    short8 vfd_ = *(const short8*)((VFPC)+384); \
    short8 pa_  = *(const short8*)(pap); \
    BAR_; \
    STAGE_((KDC), (VDC), (KT)+3); \
    QKM_((KFPN), SOUT0, SOUT1); \
    o0 = MFMA16(pa_, vfa_, o0); \
    o1 = MFMA16(pa_, vfb_, o1); \
    o2 = MFMA16(pa_, vfc_, o2); \
    o3 = MFMA16(pa_, vfd_, o3); }while(0)

  STAGE_(kd0, vd0, 0);
  STAGE_(kd1, vd1, 1);
  STAGE_(kd2, vd2, 2);
  BAR_;
  QKM_(kf0p, sA0, sA1);

  for (int it=0; it<21; ++it){
    const int kt = it*3;
    BODY_(kt,   vf0p, kd0, vd0, kf1p, sA0, sA1, sB0, sB1);
    BODY_(kt+1, vf1p, kd1, vd1, kf2p, sB0, sB1, sC0, sC1);
    BODY_(kt+2, vf2p, kd2, vd2, kf0p, sC0, sC1, sA0, sA1);
  }
  {
    SOFT_(63, sA0, sA1);
    short8 vfa_ = *(const short8*)(vf0p);
    short8 vfb_ = *(const short8*)(vf0p+128);
    short8 vfc_ = *(const short8*)(vf0p+256);
    short8 vfd_ = *(const short8*)(vf0p+384);
    asm volatile("s_waitcnt lgkmcnt(0)" ::: "memory");
    __builtin_amdgcn_sched_barrier(0);
    short8 pa_  = *(const short8*)(pap);
    o0 = MFMA16(pa_, vfa_, o0);
    o1 = MFMA16(pa_, vfb_, o1);
    o2 = MFMA16(pa_, vfc_, o2);
    o3 = MFMA16(pa_, vfd_, o3);
  }
#undef BODY_
#undef SOFT_
#undef QKM_
#undef BAR_
#undef STAGE_

  #pragma unroll
  for (int off=1; off<16; off<<=1)
    #pragma unroll
    for (int r=0;r<4;++r)
      l_run[r] += __shfl_xor(l_run[r], off, 64);

  #pragma unroll
  for (int r=0;r<4;++r){
    const int qi = q0 + lg*4 + r;
    const float linv = 1.0f / l_run[r];
    unsigned short* op = &Out[((size_t)b*2048 + qi)*1024 + h*64 + lr];
    op[0]  = f2bf(o0[r] * linv);
    op[16] = f2bf(o1[r] * linv);
    op[32] = f2bf(o2[r] * linv);
    op[48] = f2bf(o3[r] * linv);
  }
}

extern "C" void kernel_launch(void* const* d_in, const int* in_sizes, int n_in,
                              void* d_out, int out_size, void* d_ws, size_t ws_size,
                              hipStream_t stream){
  const float* x  = (const float*)d_in[0];
  const float* u  = (const float*)d_in[1];
  const float* Wq = (const float*)d_in[2];
  const float* bq = (const float*)d_in[3];
  const float* Wk = (const float*)d_in[4];
  const float* bk = (const float*)d_in[5];
  const float* Wv = (const float*)d_in[6];
  const float* bv = (const float*)d_in[7];
  const float* Wo = (const float*)d_in[8];
  const float* bo = (const float*)d_in[9];
  float* out = (float*)d_out;

  unsigned char* ws = (unsigned char*)d_ws;
  unsigned short* xb    = (unsigned short*)(ws);              // 4096x1024 bf16 (8MB)
  unsigned short* attnb = xb;                                 // reused after GEMM1
  unsigned short* Wqkvb = (unsigned short*)(ws + 8388608);    // 3072x1024 (6MB)
  unsigned short* Wob   = (unsigned short*)(ws + 14680064);   // 1024x1024 (2MB)
  unsigned short* Qb2   = (unsigned short*)(ws + 16777216);   // [B,H,S,HD] (8MB)
  unsigned short* Kb2   = (unsigned short*)(ws + 25165824);   // [B,H,S,HD] (8MB)
  unsigned short* VTb   = (unsigned short*)(ws + 33554432);   // [B,H,HD,S] (8MB)

  prep_k<<<8192, 256, 0, stream>>>(x, Wq, Wk, Wv, Wo, u, xb, Wqkvb, Wob, out);

  gemm_bt<0><<<dim3(24,32), 256, 0, stream>>>(xb, Wqkvb, bq, bk, bv,
                                              Qb2, Kb2, VTb, nullptr, 4096, 3072, 1024);
  attn_k<<<dim3(32,32), 256, 0, stream>>>(Qb2, Kb2, VTb, u, attnb);
  gemm_bt<1><<<dim3(8,32), 256, 0, stream>>>(attnb, Wob, bo, nullptr, nullptr,
                                             nullptr, nullptr, nullptr, out, 4096, 1024, 1024);
}